// Round 1
// baseline (2892.834 us; speedup 1.0000x reference)
//
#include <hip/hip_runtime.h>
#include <hip/hip_bf16.h>

// GRU T=1024 B=64 I=256 H=256.
// d_in order: X, W_fx, W_fg, b_fg, W_ix, W_ig, b_ig, W_ux, W_ug, b_ug (all f32)
// d_out: outs [T,B,H] f32 then h_last [B,H] f32.

typedef _Float16 h2 __attribute__((ext_vector_type(2)));
typedef short bf16x8 __attribute__((ext_vector_type(8)));
typedef float f32x4 __attribute__((ext_vector_type(4)));
typedef unsigned short u16;
typedef unsigned int u32;

union UQ { uint4 u; h2 h[4]; };

#if __has_builtin(__builtin_amdgcn_fdot2)
#define FDOT2(a, b, c) __builtin_amdgcn_fdot2((a), (b), (c), false)
#else
static __device__ inline float FDOT2(h2 a, h2 b, float c) {
    return c + (float)a[0] * (float)b[0] + (float)a[1] * (float)b[1];
}
#endif

__device__ inline u16 f2bf(float f) {
    u32 u = __float_as_uint(f);
    u = (u + 0x7FFF + ((u >> 16) & 1)) >> 16;   // RNE
    return (u16)u;
}

// ---------------- prep: WcatT [768][256] bf16: WcatT[g*256+j][k] = Wgx[k][j]
__global__ void prep_wcat(const float* __restrict__ Wfx, const float* __restrict__ Wix,
                          const float* __restrict__ Wux, u16* __restrict__ WcatT) {
    int n = blockIdx.x;            // 0..767
    int k = threadIdx.x;           // 0..255
    int g = n >> 8, j = n & 255;
    const float* W = (g == 0) ? Wfx : (g == 1) ? Wix : Wux;
    WcatT[(size_t)n * 256 + k] = f2bf(W[(size_t)k * 256 + j]);
}

// ---------------- prep: WT f16 [3][256][256]: WT[g][j][i] = Wg[i][j] + bg[j]
__global__ void prep_wrec(const float* __restrict__ Wfg, const float* __restrict__ bfg,
                          const float* __restrict__ Wig, const float* __restrict__ big,
                          const float* __restrict__ Wug, const float* __restrict__ bug,
                          _Float16* __restrict__ WT) {
    int n = blockIdx.x;            // 0..767
    int i = threadIdx.x;           // 0..255
    int g = n >> 8, j = n & 255;
    const float* W = (g == 0) ? Wfg : (g == 1) ? Wig : Wug;
    const float* bv = (g == 0) ? bfg : (g == 1) ? big : bug;
    WT[(size_t)n * 256 + i] = (_Float16)(W[(size_t)i * 256 + j] + bv[j]);
}

// ---------------- projection GEMM: proj[65536][768] f16 = X[65536][256] @ Wcat[256][768]
// bf16 MFMA 16x16x32, tile 128x128, BK=32, 4 waves (2x2), wave tile 64x64.
__global__ __launch_bounds__(256) void proj_gemm(const float* __restrict__ X,
                                                 const u16* __restrict__ WT, // WcatT [768][256]
                                                 _Float16* __restrict__ proj) {
    __shared__ u16 shA[128][32];        // A tile bf16 (row, k)
    __shared__ u16 shB[128][32];        // B tile bf16 (colN, k)  (transposed)
    __shared__ _Float16 shC[128][128];  // epilogue staging (32KB)

    int tid = threadIdx.x;
    int bn = blockIdx.x % 6, bm = blockIdx.x / 6;
    int lane = tid & 63, wv = tid >> 6;
    int wr = wv >> 1, wc = wv & 1;      // 2x2 waves

    f32x4 acc[4][4];
#pragma unroll
    for (int m = 0; m < 4; m++)
#pragma unroll
        for (int n = 0; n < 4; n++) acc[m][n] = (f32x4){0.f, 0.f, 0.f, 0.f};

    for (int kt = 0; kt < 8; ++kt) {
        // stage A: 128 rows x 32 k, f32 -> bf16
#pragma unroll
        for (int q = 0; q < 4; ++q) {
            int g = tid + 256 * q;          // 0..1023 float4 groups
            int r = g >> 3, c4 = g & 7;
            const float4 v = *(const float4*)(X + (size_t)(bm * 128 + r) * 256 + kt * 32 + c4 * 4);
            ushort4 o;
            o.x = f2bf(v.x); o.y = f2bf(v.y); o.z = f2bf(v.z); o.w = f2bf(v.w);
            *(ushort4*)&shA[r][c4 * 4] = o;
        }
        // stage B: 128 cols x 32 k from WcatT (already bf16, n-major)
#pragma unroll
        for (int q = 0; q < 2; ++q) {
            int g = tid + 256 * q;          // 0..511 16B groups
            int r = g >> 2, c8 = g & 3;
            uint4 v = *(const uint4*)(WT + (size_t)(bn * 128 + r) * 256 + kt * 32 + c8 * 8);
            *(uint4*)&shB[r][c8 * 8] = v;
        }
        __syncthreads();

        bf16x8 af[4], bf[4];
#pragma unroll
        for (int m = 0; m < 4; m++)
            af[m] = *(const bf16x8*)&shA[wr * 64 + m * 16 + (lane & 15)][(lane >> 4) * 8];
#pragma unroll
        for (int n = 0; n < 4; n++)
            bf[n] = *(const bf16x8*)&shB[wc * 64 + n * 16 + (lane & 15)][(lane >> 4) * 8];
#pragma unroll
        for (int m = 0; m < 4; m++)
#pragma unroll
            for (int n = 0; n < 4; n++)
                acc[m][n] = __builtin_amdgcn_mfma_f32_16x16x32_bf16(af[m], bf[n], acc[m][n], 0, 0, 0);
        __syncthreads();
    }

    // epilogue: acc -> LDS f16 -> coalesced global stores
#pragma unroll
    for (int m = 0; m < 4; m++)
#pragma unroll
        for (int n = 0; n < 4; n++)
#pragma unroll
            for (int r = 0; r < 4; r++) {
                int row = wr * 64 + m * 16 + (lane >> 4) * 4 + r;
                int col = wc * 64 + n * 16 + (lane & 15);
                shC[row][col] = (_Float16)acc[m][n][r];
            }
    __syncthreads();
    {
        int row = tid >> 1, hf = tid & 1;
        size_t gbase = (size_t)(bm * 128 + row) * 768 + bn * 128 + hf * 64;
        const uint4* src = (const uint4*)&shC[row][hf * 64];
        uint4* dst = (uint4*)(proj + gbase);
#pragma unroll
        for (int q = 0; q < 8; q++) dst[q] = src[q];
    }
}

// ---------------- recurrence: 64 WGs (one per batch), 256 threads (one per column j).
// Weights in registers (384 x half2), h f32 in-register + f16 pairs in LDS.
__global__ __launch_bounds__(256) void gru_rec(const _Float16* __restrict__ proj,
                                               const _Float16* __restrict__ WT,
                                               float* __restrict__ out) {
    int b = blockIdx.x;        // batch
    int j = threadIdx.x;       // column 0..255

    __shared__ __align__(16) _Float16 sh_h[256];
    __shared__ __align__(16) _Float16 sh_rh[256];

    // load this thread's weight columns (transposed rows): 3 x 256 f16
    h2 wf[128], wi[128], wu[128];
    const uint4* pf = (const uint4*)(WT + (size_t)j * 256);
    const uint4* pi = (const uint4*)(WT + 65536 + (size_t)j * 256);
    const uint4* pu = (const uint4*)(WT + 131072 + (size_t)j * 256);
#pragma unroll
    for (int m = 0; m < 32; m++) {
        UQ a; a.u = pf[m];
        wf[4 * m] = a.h[0]; wf[4 * m + 1] = a.h[1]; wf[4 * m + 2] = a.h[2]; wf[4 * m + 3] = a.h[3];
    }
#pragma unroll
    for (int m = 0; m < 32; m++) {
        UQ a; a.u = pi[m];
        wi[4 * m] = a.h[0]; wi[4 * m + 1] = a.h[1]; wi[4 * m + 2] = a.h[2]; wi[4 * m + 3] = a.h[3];
    }
#pragma unroll
    for (int m = 0; m < 32; m++) {
        UQ a; a.u = pu[m];
        wu[4 * m] = a.h[0]; wu[4 * m + 1] = a.h[1]; wu[4 * m + 2] = a.h[2]; wu[4 * m + 3] = a.h[3];
    }

    sh_h[j] = (_Float16)0.f;
    float hreg = 0.f;

    const _Float16* prow = proj + (size_t)b * 768 + j;  // row t*64+b, step stride 64*768
    float xf = (float)prow[0];
    float xi = (float)prow[256];
    float xu = (float)prow[512];

    __syncthreads();

    for (int t = 0; t < 1024; ++t) {
        // phase 1: accf = h . Wf[:,j], acci = h . Wi[:,j]
        float accf = 0.f, accf1 = 0.f, acci = 0.f, acci1 = 0.f;
#pragma unroll
        for (int m = 0; m < 32; m++) {
            UQ a; a.u = ((const uint4*)sh_h)[m];
            accf  = FDOT2(wf[4 * m],     a.h[0], accf);
            accf1 = FDOT2(wf[4 * m + 1], a.h[1], accf1);
            acci  = FDOT2(wi[4 * m],     a.h[0], acci);
            acci1 = FDOT2(wi[4 * m + 1], a.h[1], acci1);
            accf  = FDOT2(wf[4 * m + 2], a.h[2], accf);
            accf1 = FDOT2(wf[4 * m + 3], a.h[3], accf1);
            acci  = FDOT2(wi[4 * m + 2], a.h[2], acci);
            acci1 = FDOT2(wi[4 * m + 3], a.h[3], acci1);
        }
        float reset = 1.f / (1.f + __expf(-(xf + accf + accf1)));
        float upd   = 1.f / (1.f + __expf(-(xi + acci + acci1)));
        sh_rh[j] = (_Float16)(reset * hreg);

        // prefetch next-step projections (consumed next iteration)
        _Float16 rxf = (_Float16)0.f, rxi = (_Float16)0.f, rxu = (_Float16)0.f;
        if (t < 1023) {
            const _Float16* p2 = prow + 49152;
            rxf = p2[0]; rxi = p2[256]; rxu = p2[512];
        }
        __syncthreads();   // rh ready

        // phase 3: accu = (reset*h) . Wu[:,j]
        float au0 = 0.f, au1 = 0.f, au2 = 0.f, au3 = 0.f;
#pragma unroll
        for (int m = 0; m < 32; m++) {
            UQ a; a.u = ((const uint4*)sh_rh)[m];
            au0 = FDOT2(wu[4 * m],     a.h[0], au0);
            au1 = FDOT2(wu[4 * m + 1], a.h[1], au1);
            au2 = FDOT2(wu[4 * m + 2], a.h[2], au2);
            au3 = FDOT2(wu[4 * m + 3], a.h[3], au3);
        }
        float zc = xu + ((au0 + au1) + (au2 + au3));
        float e = __expf(2.f * zc);
        float cand = (e - 1.f) / (e + 1.f);     // tanh
        hreg = upd * hreg + (1.f - upd) * cand;

        out[((size_t)t * 64 + b) * 256 + j] = hreg;
        sh_h[j] = (_Float16)hreg;
        __syncthreads();   // h ready for next step

        xf = (float)rxf; xi = (float)rxi; xu = (float)rxu;
        prow += 49152;
    }

    out[(size_t)1024 * 64 * 256 + (size_t)b * 256 + j] = hreg;
}

extern "C" void kernel_launch(void* const* d_in, const int* in_sizes, int n_in,
                              void* d_out, int out_size, void* d_ws, size_t ws_size,
                              hipStream_t stream) {
    const float* X   = (const float*)d_in[0];
    const float* Wfx = (const float*)d_in[1];
    const float* Wfg = (const float*)d_in[2];
    const float* bfg = (const float*)d_in[3];
    const float* Wix = (const float*)d_in[4];
    const float* Wig = (const float*)d_in[5];
    const float* big = (const float*)d_in[6];
    const float* Wux = (const float*)d_in[7];
    const float* Wug = (const float*)d_in[8];
    const float* bug = (const float*)d_in[9];
    float* out = (float*)d_out;

    char* ws = (char*)d_ws;
    _Float16* proj = (_Float16*)ws;                          // 65536*768*2 = 100663296 B
    u16* WcatT = (u16*)(ws + 100663296);                     // 768*256*2   = 393216 B
    _Float16* WT = (_Float16*)(ws + 100663296 + 393216);     // 3*256*256*2 = 393216 B

    prep_wcat<<<768, 256, 0, stream>>>(Wfx, Wix, Wux, WcatT);
    prep_wrec<<<768, 256, 0, stream>>>(Wfg, bfg, Wig, big, Wug, bug, WT);
    proj_gemm<<<3072, 256, 0, stream>>>(X, WcatT, proj);
    gru_rec<<<64, 256, 0, stream>>>(proj, WT, out);
}

// Round 2
// 2889.629 us; speedup vs baseline: 1.0011x; 1.0011x over previous
//
#include <hip/hip_runtime.h>
#include <hip/hip_bf16.h>

// GRU T=1024 B=64 I=256 H=256.
// d_in order: X, W_fx, W_fg, b_fg, W_ix, W_ig, b_ig, W_ux, W_ug, b_ug (all f32)
// d_out: outs [T,B,H] f32 then h_last [B,H] f32.

typedef _Float16 h2 __attribute__((ext_vector_type(2)));
typedef short bf16x8 __attribute__((ext_vector_type(8)));
typedef float f32x4 __attribute__((ext_vector_type(4)));
typedef unsigned short u16;
typedef unsigned int u32;

union UQ { uint4 u; h2 h[4]; };

#if __has_builtin(__builtin_amdgcn_fdot2)
#define FDOT2(a, b, c) __builtin_amdgcn_fdot2((a), (b), (c), false)
#else
static __device__ inline float FDOT2(h2 a, h2 b, float c) {
    return c + (float)a[0] * (float)b[0] + (float)a[1] * (float)b[1];
}
#endif

__device__ inline u16 f2bf(float f) {
    u32 u = __float_as_uint(f);
    u = (u + 0x7FFF + ((u >> 16) & 1)) >> 16;   // RNE
    return (u16)u;
}

// Raw workgroup barrier: no vmcnt drain (global loads/stores here are
// thread-private, so they may stay in flight across the barrier).
__device__ inline void wg_barrier() {
    asm volatile("s_waitcnt lgkmcnt(0)" ::: "memory");
    __builtin_amdgcn_s_barrier();
    asm volatile("" ::: "memory");
}

// ---------------- prep: WcatT [768][256] bf16: WcatT[g*256+j][k] = Wgx[k][j]
__global__ void prep_wcat(const float* __restrict__ Wfx, const float* __restrict__ Wix,
                          const float* __restrict__ Wux, u16* __restrict__ WcatT) {
    int n = blockIdx.x;            // 0..767
    int k = threadIdx.x;           // 0..255
    int g = n >> 8, j = n & 255;
    const float* W = (g == 0) ? Wfx : (g == 1) ? Wix : Wux;
    WcatT[(size_t)n * 256 + k] = f2bf(W[(size_t)k * 256 + j]);
}

// ---------------- prep: WT f16 [3][256][256]: WT[g][j][i] = Wg[i][j] + bg[j]
__global__ void prep_wrec(const float* __restrict__ Wfg, const float* __restrict__ bfg,
                          const float* __restrict__ Wig, const float* __restrict__ big,
                          const float* __restrict__ Wug, const float* __restrict__ bug,
                          _Float16* __restrict__ WT) {
    int n = blockIdx.x;            // 0..767
    int i = threadIdx.x;           // 0..255
    int g = n >> 8, j = n & 255;
    const float* W = (g == 0) ? Wfg : (g == 1) ? Wig : Wug;
    const float* bv = (g == 0) ? bfg : (g == 1) ? big : bug;
    WT[(size_t)n * 256 + i] = (_Float16)(W[(size_t)i * 256 + j] + bv[j]);
}

// ---------------- projection GEMM: proj[65536][768] f16 = X[65536][256] @ Wcat[256][768]
// bf16 MFMA 16x16x32, tile 128x128, BK=32, 4 waves (2x2), wave tile 64x64.
__global__ __launch_bounds__(256) void proj_gemm(const float* __restrict__ X,
                                                 const u16* __restrict__ WT, // WcatT [768][256]
                                                 _Float16* __restrict__ proj) {
    __shared__ u16 shA[128][32];        // A tile bf16 (row, k)
    __shared__ u16 shB[128][32];        // B tile bf16 (colN, k)  (transposed)
    __shared__ _Float16 shC[128][128];  // epilogue staging (32KB)

    int tid = threadIdx.x;
    int bn = blockIdx.x % 6, bm = blockIdx.x / 6;
    int lane = tid & 63, wv = tid >> 6;
    int wr = wv >> 1, wc = wv & 1;      // 2x2 waves

    f32x4 acc[4][4];
#pragma unroll
    for (int m = 0; m < 4; m++)
#pragma unroll
        for (int n = 0; n < 4; n++) acc[m][n] = (f32x4){0.f, 0.f, 0.f, 0.f};

    for (int kt = 0; kt < 8; ++kt) {
        // stage A: 128 rows x 32 k, f32 -> bf16
#pragma unroll
        for (int q = 0; q < 4; ++q) {
            int g = tid + 256 * q;          // 0..1023 float4 groups
            int r = g >> 3, c4 = g & 7;
            const float4 v = *(const float4*)(X + (size_t)(bm * 128 + r) * 256 + kt * 32 + c4 * 4);
            ushort4 o;
            o.x = f2bf(v.x); o.y = f2bf(v.y); o.z = f2bf(v.z); o.w = f2bf(v.w);
            *(ushort4*)&shA[r][c4 * 4] = o;
        }
        // stage B: 128 cols x 32 k from WcatT (already bf16, n-major)
#pragma unroll
        for (int q = 0; q < 2; ++q) {
            int g = tid + 256 * q;          // 0..511 16B groups
            int r = g >> 2, c8 = g & 3;
            uint4 v = *(const uint4*)(WT + (size_t)(bn * 128 + r) * 256 + kt * 32 + c8 * 8);
            *(uint4*)&shB[r][c8 * 8] = v;
        }
        __syncthreads();

        bf16x8 af[4], bf[4];
#pragma unroll
        for (int m = 0; m < 4; m++)
            af[m] = *(const bf16x8*)&shA[wr * 64 + m * 16 + (lane & 15)][(lane >> 4) * 8];
#pragma unroll
        for (int n = 0; n < 4; n++)
            bf[n] = *(const bf16x8*)&shB[wc * 64 + n * 16 + (lane & 15)][(lane >> 4) * 8];
#pragma unroll
        for (int m = 0; m < 4; m++)
#pragma unroll
            for (int n = 0; n < 4; n++)
                acc[m][n] = __builtin_amdgcn_mfma_f32_16x16x32_bf16(af[m], bf[n], acc[m][n], 0, 0, 0);
        __syncthreads();
    }

    // epilogue: acc -> LDS f16 -> coalesced global stores
#pragma unroll
    for (int m = 0; m < 4; m++)
#pragma unroll
        for (int n = 0; n < 4; n++)
#pragma unroll
            for (int r = 0; r < 4; r++) {
                int row = wr * 64 + m * 16 + (lane >> 4) * 4 + r;
                int col = wc * 64 + n * 16 + (lane & 15);
                shC[row][col] = (_Float16)acc[m][n][r];
            }
    __syncthreads();
    {
        int row = tid >> 1, hf = tid & 1;
        size_t gbase = (size_t)(bm * 128 + row) * 768 + bn * 128 + hf * 64;
        const uint4* src = (const uint4*)&shC[row][hf * 64];
        uint4* dst = (uint4*)(proj + gbase);
#pragma unroll
        for (int q = 0; q < 8; q++) dst[q] = src[q];
    }
}

// ---------------- recurrence: 64 WGs (one per batch), 256 threads (one per column j).
// One WG per CU -> 1 wave/SIMD -> up to 512 VGPRs/lane. Weights (3x256 f16 =
// 384 VGPRs) MUST be register-resident: __launch_bounds__(256, 1).
__global__ __launch_bounds__(256, 1) void gru_rec(const _Float16* __restrict__ proj,
                                                  const _Float16* __restrict__ WT,
                                                  float* __restrict__ out) {
    int b = blockIdx.x;        // batch
    int j = threadIdx.x;       // column 0..255

    __shared__ __align__(16) _Float16 sh_h[256];
    __shared__ __align__(16) _Float16 sh_rh[256];

    // load this thread's weight columns (transposed rows): 3 x 256 f16
    h2 wf[128], wi[128], wu[128];
    const uint4* pf = (const uint4*)(WT + (size_t)j * 256);
    const uint4* pi = (const uint4*)(WT + 65536 + (size_t)j * 256);
    const uint4* pu = (const uint4*)(WT + 131072 + (size_t)j * 256);
#pragma unroll
    for (int m = 0; m < 32; m++) {
        UQ a; a.u = pf[m];
        wf[4 * m] = a.h[0]; wf[4 * m + 1] = a.h[1]; wf[4 * m + 2] = a.h[2]; wf[4 * m + 3] = a.h[3];
    }
#pragma unroll
    for (int m = 0; m < 32; m++) {
        UQ a; a.u = pi[m];
        wi[4 * m] = a.h[0]; wi[4 * m + 1] = a.h[1]; wi[4 * m + 2] = a.h[2]; wi[4 * m + 3] = a.h[3];
    }
#pragma unroll
    for (int m = 0; m < 32; m++) {
        UQ a; a.u = pu[m];
        wu[4 * m] = a.h[0]; wu[4 * m + 1] = a.h[1]; wu[4 * m + 2] = a.h[2]; wu[4 * m + 3] = a.h[3];
    }

    sh_h[j] = (_Float16)0.f;
    float hreg = 0.f;

    const _Float16* prow = proj + (size_t)b * 768 + j;  // row t*64+b, step stride 64*768
    float xf = (float)prow[0];
    float xi = (float)prow[256];
    float xu = (float)prow[512];

    float* outp = out + (size_t)b * 256 + j;            // step stride 64*256 f32

    wg_barrier();

    for (int t = 0; t < 1024; ++t) {
        // prefetch next-step projections early (consumed after barrier 2);
        // with raw barriers these loads stay in flight across both barriers.
        _Float16 rxf = (_Float16)0.f, rxi = (_Float16)0.f, rxu = (_Float16)0.f;
        if (t < 1023) {
            const _Float16* p2 = prow + 49152;
            rxf = p2[0]; rxi = p2[256]; rxu = p2[512];
        }

        // phase A: accf = h . Wf[:,j], acci = h . Wi[:,j]  (uniform-address
        // broadcast b128 reads of sh_h -> no bank conflicts)
        float accf = 0.f, accf1 = 0.f, acci = 0.f, acci1 = 0.f;
#pragma unroll
        for (int m = 0; m < 32; m++) {
            UQ a; a.u = ((const uint4*)sh_h)[m];
            accf  = FDOT2(wf[4 * m],     a.h[0], accf);
            accf1 = FDOT2(wf[4 * m + 1], a.h[1], accf1);
            acci  = FDOT2(wi[4 * m],     a.h[0], acci);
            acci1 = FDOT2(wi[4 * m + 1], a.h[1], acci1);
            accf  = FDOT2(wf[4 * m + 2], a.h[2], accf);
            accf1 = FDOT2(wf[4 * m + 3], a.h[3], accf1);
            acci  = FDOT2(wi[4 * m + 2], a.h[2], acci);
            acci1 = FDOT2(wi[4 * m + 3], a.h[3], acci1);
        }
        float reset = 1.f / (1.f + __expf(-(xf + accf + accf1)));
        float upd   = 1.f / (1.f + __expf(-(xi + acci + acci1)));
        sh_rh[j] = (_Float16)(reset * hreg);

        wg_barrier();   // rh ready

        // phase B: accu = (reset*h) . Wu[:,j]
        float au0 = 0.f, au1 = 0.f, au2 = 0.f, au3 = 0.f;
#pragma unroll
        for (int m = 0; m < 32; m++) {
            UQ a; a.u = ((const uint4*)sh_rh)[m];
            au0 = FDOT2(wu[4 * m],     a.h[0], au0);
            au1 = FDOT2(wu[4 * m + 1], a.h[1], au1);
            au2 = FDOT2(wu[4 * m + 2], a.h[2], au2);
            au3 = FDOT2(wu[4 * m + 3], a.h[3], au3);
        }
        float zc = xu + ((au0 + au1) + (au2 + au3));
        float e = __expf(2.f * zc);
        float cand = (e - 1.f) / (e + 1.f);     // tanh
        hreg = upd * hreg + (1.f - upd) * cand;

        *outp = hreg;                 // fire-and-forget, never drained by barrier
        sh_h[j] = (_Float16)hreg;

        wg_barrier();   // h ready for next step

        xf = (float)rxf; xi = (float)rxi; xu = (float)rxu;
        prow += 49152;
        outp += 16384;
    }

    out[(size_t)1024 * 64 * 256 + (size_t)b * 256 + j] = hreg;
}

extern "C" void kernel_launch(void* const* d_in, const int* in_sizes, int n_in,
                              void* d_out, int out_size, void* d_ws, size_t ws_size,
                              hipStream_t stream) {
    const float* X   = (const float*)d_in[0];
    const float* Wfx = (const float*)d_in[1];
    const float* Wfg = (const float*)d_in[2];
    const float* bfg = (const float*)d_in[3];
    const float* Wix = (const float*)d_in[4];
    const float* Wig = (const float*)d_in[5];
    const float* big = (const float*)d_in[6];
    const float* Wux = (const float*)d_in[7];
    const float* Wug = (const float*)d_in[8];
    const float* bug = (const float*)d_in[9];
    float* out = (float*)d_out;

    char* ws = (char*)d_ws;
    _Float16* proj = (_Float16*)ws;                          // 65536*768*2 = 100663296 B
    u16* WcatT = (u16*)(ws + 100663296);                     // 768*256*2   = 393216 B
    _Float16* WT = (_Float16*)(ws + 100663296 + 393216);     // 3*256*256*2 = 393216 B

    prep_wcat<<<768, 256, 0, stream>>>(Wfx, Wix, Wux, WcatT);
    prep_wrec<<<768, 256, 0, stream>>>(Wfg, bfg, Wig, big, Wug, bug, WT);
    proj_gemm<<<3072, 256, 0, stream>>>(X, WcatT, proj);
    gru_rec<<<64, 256, 0, stream>>>(proj, WT, out);
}

// Round 3
// 1786.588 us; speedup vs baseline: 1.6192x; 1.6174x over previous
//
#include <hip/hip_runtime.h>
#include <hip/hip_bf16.h>

// GRU T=1024 B=64 I=256 H=256.
// d_in order: X, W_fx, W_fg, b_fg, W_ix, W_ig, b_ig, W_ux, W_ug, b_ug (all f32)
// d_out: outs [T,B,H] f32 then h_last [B,H] f32.

typedef _Float16 h2 __attribute__((ext_vector_type(2)));
typedef short bf16x8 __attribute__((ext_vector_type(8)));
typedef float f32x4 __attribute__((ext_vector_type(4)));
typedef unsigned short u16;
typedef unsigned int u32;

union UQ { uint4 u; h2 h[4]; };

#if __has_builtin(__builtin_amdgcn_fdot2)
#define FDOT2(a, b, c) __builtin_amdgcn_fdot2((a), (b), (c), false)
#else
static __device__ inline float FDOT2(h2 a, h2 b, float c) {
    return c + (float)a[0] * (float)b[0] + (float)a[1] * (float)b[1];
}
#endif

__device__ inline u16 f2bf(float f) {
    u32 u = __float_as_uint(f);
    u = (u + 0x7FFF + ((u >> 16) & 1)) >> 16;   // RNE
    return (u16)u;
}

// Opaque pin: makes the value's origin invisible -> compiler cannot re-sink
// the defining load into the loop; value must stay register-resident.
__device__ inline void pin(h2& x) { asm volatile("" : "+v"(x)); }

// Raw workgroup barrier: LDS-visibility only, no vmcnt drain (global
// loads/stores here are thread-private and may stay in flight).
__device__ inline void wg_barrier() {
    asm volatile("s_waitcnt lgkmcnt(0)" ::: "memory");
    __builtin_amdgcn_s_barrier();
    asm volatile("" ::: "memory");
}

// ---------------- prep: WcatT [768][256] bf16: WcatT[g*256+j][k] = Wgx[k][j]
__global__ void prep_wcat(const float* __restrict__ Wfx, const float* __restrict__ Wix,
                          const float* __restrict__ Wux, u16* __restrict__ WcatT) {
    int n = blockIdx.x;            // 0..767
    int k = threadIdx.x;           // 0..255
    int g = n >> 8, j = n & 255;
    const float* W = (g == 0) ? Wfx : (g == 1) ? Wix : Wux;
    WcatT[(size_t)n * 256 + k] = f2bf(W[(size_t)k * 256 + j]);
}

// ---------------- prep: WT f16 [3][256][256]: WT[g][j][i] = Wg[i][j] + bg[j]
__global__ void prep_wrec(const float* __restrict__ Wfg, const float* __restrict__ bfg,
                          const float* __restrict__ Wig, const float* __restrict__ big,
                          const float* __restrict__ Wug, const float* __restrict__ bug,
                          _Float16* __restrict__ WT) {
    int n = blockIdx.x;            // 0..767
    int i = threadIdx.x;           // 0..255
    int g = n >> 8, j = n & 255;
    const float* W = (g == 0) ? Wfg : (g == 1) ? Wig : Wug;
    const float* bv = (g == 0) ? bfg : (g == 1) ? big : bug;
    WT[(size_t)n * 256 + i] = (_Float16)(W[(size_t)i * 256 + j] + bv[j]);
}

// ---------------- projection GEMM: proj[65536][768] f16 = X[65536][256] @ Wcat[256][768]
__global__ __launch_bounds__(256) void proj_gemm(const float* __restrict__ X,
                                                 const u16* __restrict__ WT, // WcatT [768][256]
                                                 _Float16* __restrict__ proj) {
    __shared__ u16 shA[128][32];
    __shared__ u16 shB[128][32];
    __shared__ _Float16 shC[128][128];

    int tid = threadIdx.x;
    int bn = blockIdx.x % 6, bm = blockIdx.x / 6;
    int lane = tid & 63, wv = tid >> 6;
    int wr = wv >> 1, wc = wv & 1;

    f32x4 acc[4][4];
#pragma unroll
    for (int m = 0; m < 4; m++)
#pragma unroll
        for (int n = 0; n < 4; n++) acc[m][n] = (f32x4){0.f, 0.f, 0.f, 0.f};

    for (int kt = 0; kt < 8; ++kt) {
#pragma unroll
        for (int q = 0; q < 4; ++q) {
            int g = tid + 256 * q;
            int r = g >> 3, c4 = g & 7;
            const float4 v = *(const float4*)(X + (size_t)(bm * 128 + r) * 256 + kt * 32 + c4 * 4);
            ushort4 o;
            o.x = f2bf(v.x); o.y = f2bf(v.y); o.z = f2bf(v.z); o.w = f2bf(v.w);
            *(ushort4*)&shA[r][c4 * 4] = o;
        }
#pragma unroll
        for (int q = 0; q < 2; ++q) {
            int g = tid + 256 * q;
            int r = g >> 2, c8 = g & 3;
            uint4 v = *(const uint4*)(WT + (size_t)(bn * 128 + r) * 256 + kt * 32 + c8 * 8);
            *(uint4*)&shB[r][c8 * 8] = v;
        }
        __syncthreads();

        bf16x8 af[4], bfr[4];
#pragma unroll
        for (int m = 0; m < 4; m++)
            af[m] = *(const bf16x8*)&shA[wr * 64 + m * 16 + (lane & 15)][(lane >> 4) * 8];
#pragma unroll
        for (int n = 0; n < 4; n++)
            bfr[n] = *(const bf16x8*)&shB[wc * 64 + n * 16 + (lane & 15)][(lane >> 4) * 8];
#pragma unroll
        for (int m = 0; m < 4; m++)
#pragma unroll
            for (int n = 0; n < 4; n++)
                acc[m][n] = __builtin_amdgcn_mfma_f32_16x16x32_bf16(af[m], bfr[n], acc[m][n], 0, 0, 0);
        __syncthreads();
    }

#pragma unroll
    for (int m = 0; m < 4; m++)
#pragma unroll
        for (int n = 0; n < 4; n++)
#pragma unroll
            for (int r = 0; r < 4; r++) {
                int row = wr * 64 + m * 16 + (lane >> 4) * 4 + r;
                int col = wc * 64 + n * 16 + (lane & 15);
                shC[row][col] = (_Float16)acc[m][n][r];
            }
    __syncthreads();
    {
        int row = tid >> 1, hf = tid & 1;
        size_t gbase = (size_t)(bm * 128 + row) * 768 + bn * 128 + hf * 64;
        const uint4* src = (const uint4*)&shC[row][hf * 64];
        uint4* dst = (uint4*)(proj + gbase);
#pragma unroll
        for (int q = 0; q < 8; q++) dst[q] = src[q];
    }
}

// ---------------- recurrence: 64 WGs (one per batch), 512 threads.
// Thread (p = tid>>8, j = tid&255): p=0 owns f-gate full dot for column j,
// p=1 owns i-gate full dot; u-gate dot split in i-halves across p.
// Per-thread weights: 128 + 64 = 192 h2 regs (fits 256-VGPR arch cap at
// 2 waves/SIMD). Pinned so LLVM can't re-stream them from L2 each step.
__global__ __launch_bounds__(512, 2) void gru_rec(const _Float16* __restrict__ proj,
                                                  const _Float16* __restrict__ WT,
                                                  float* __restrict__ out) {
    int b = blockIdx.x;
    int tid = threadIdx.x;
    int j = tid & 255;
    int p = tid >> 8;          // wave-uniform (4 waves per half)

    __shared__ __align__(16) _Float16 sh_h[256];   // f16 h (for dots)
    __shared__ __align__(16) _Float16 sh_rh[256];  // f16 reset*h
    __shared__ __align__(16) float sh_hf[256];     // f32 h (exact state)
    __shared__ __align__(16) float sh_pu[512];     // u-gate partials

    // weights: own gate (256 f16) + u-gate half (128 f16)
    h2 wg[128], wu[64];
    {
        const uint4* pg = (const uint4*)(WT + (size_t)p * 65536 + (size_t)j * 256);
#pragma unroll
        for (int m = 0; m < 32; m++) {
            UQ a; a.u = pg[m];
            wg[4 * m] = a.h[0]; wg[4 * m + 1] = a.h[1];
            wg[4 * m + 2] = a.h[2]; wg[4 * m + 3] = a.h[3];
        }
        const uint4* pu4 = (const uint4*)(WT + 131072 + (size_t)j * 256 + p * 128);
#pragma unroll
        for (int m = 0; m < 16; m++) {
            UQ a; a.u = pu4[m];
            wu[4 * m] = a.h[0]; wu[4 * m + 1] = a.h[1];
            wu[4 * m + 2] = a.h[2]; wu[4 * m + 3] = a.h[3];
        }
    }
#pragma unroll
    for (int m = 0; m < 128; m++) pin(wg[m]);
#pragma unroll
    for (int m = 0; m < 64; m++) pin(wu[m]);

    if (p == 0) { sh_h[j] = (_Float16)0.f; sh_hf[j] = 0.f; }
    __syncthreads();

    // x streams: p=0 -> xf at prow[0]; p=1 -> xi at prow[0], xu at prow[256]
    const _Float16* prow = proj + (size_t)b * 768 + (size_t)p * 256 + j;
    float x0 = (float)prow[0];
    float x1 = (p == 1) ? (float)prow[256] : 0.f;
    float* outp = out + (size_t)b * 256 + j;
    float hlast = 0.f;

    for (int t = 0; t < 1024; ++t) {
        // prefetch next step's x (stays in flight across barriers)
        _Float16 r0 = (_Float16)0.f, r1 = (_Float16)0.f;
        if (t < 1023) {
            r0 = prow[49152];
            if (p == 1) r1 = prow[49152 + 256];
        }

        float hcur = sh_hf[j];   // f32 h, stride-4 b32 read, conflict-free

        // phase A: own-gate full dot over sh_h (broadcast b128 reads)
        float a0 = 0.f, a1 = 0.f, a2 = 0.f, a3 = 0.f;
        {
            const uint4* hh = (const uint4*)sh_h;
#pragma unroll
            for (int m = 0; m < 32; m++) {
                UQ a; a.u = hh[m];
                a0 = FDOT2(wg[4 * m],     a.h[0], a0);
                a1 = FDOT2(wg[4 * m + 1], a.h[1], a1);
                a2 = FDOT2(wg[4 * m + 2], a.h[2], a2);
                a3 = FDOT2(wg[4 * m + 3], a.h[3], a3);
            }
        }
        float dg = (a0 + a1) + (a2 + a3);
        float gate = 1.f / (1.f + __expf(-(x0 + dg)));   // p=0: reset, p=1: update
        if (p == 0) sh_rh[j] = (_Float16)(gate * hcur);

        wg_barrier();   // B1: rh visible

        // phase B: u-gate partial dot over own i-half of sh_rh
        float u0 = 0.f, u1 = 0.f, u2 = 0.f, u3 = 0.f;
        {
            const uint4* rr = (const uint4*)sh_rh + p * 16;
#pragma unroll
            for (int m = 0; m < 16; m++) {
                UQ a; a.u = rr[m];
                u0 = FDOT2(wu[4 * m],     a.h[0], u0);
                u1 = FDOT2(wu[4 * m + 1], a.h[1], u1);
                u2 = FDOT2(wu[4 * m + 2], a.h[2], u2);
                u3 = FDOT2(wu[4 * m + 3], a.h[3], u3);
            }
        }
        sh_pu[tid] = (u0 + u1) + (u2 + u3);

        wg_barrier();   // B2: partials visible

        if (p == 1) {
            float accu = sh_pu[j] + sh_pu[j + 256];
            float zc = x1 + accu;
            float e = __expf(2.f * zc);
            float cand = (e - 1.f) / (e + 1.f);          // tanh
            float hn = gate * hcur + (1.f - gate) * cand; // gate == update
            sh_hf[j] = hn;
            sh_h[j] = (_Float16)hn;
            *outp = hn;                                   // fire-and-forget
            hlast = hn;
        }

        wg_barrier();   // B3: new h visible

        x0 = (float)r0;
        x1 = (p == 1) ? (float)r1 : 0.f;
        prow += 49152;
        outp += 16384;
    }

    if (p == 1) out[(size_t)16777216 + (size_t)b * 256 + j] = hlast;
}

extern "C" void kernel_launch(void* const* d_in, const int* in_sizes, int n_in,
                              void* d_out, int out_size, void* d_ws, size_t ws_size,
                              hipStream_t stream) {
    const float* X   = (const float*)d_in[0];
    const float* Wfx = (const float*)d_in[1];
    const float* Wfg = (const float*)d_in[2];
    const float* bfg = (const float*)d_in[3];
    const float* Wix = (const float*)d_in[4];
    const float* Wig = (const float*)d_in[5];
    const float* big = (const float*)d_in[6];
    const float* Wux = (const float*)d_in[7];
    const float* Wug = (const float*)d_in[8];
    const float* bug = (const float*)d_in[9];
    float* out = (float*)d_out;

    char* ws = (char*)d_ws;
    _Float16* proj = (_Float16*)ws;                          // 65536*768*2 = 100663296 B
    u16* WcatT = (u16*)(ws + 100663296);                     // 768*256*2   = 393216 B
    _Float16* WT = (_Float16*)(ws + 100663296 + 393216);     // 3*256*256*2 = 393216 B

    prep_wcat<<<768, 256, 0, stream>>>(Wfx, Wix, Wux, WcatT);
    prep_wrec<<<768, 256, 0, stream>>>(Wfg, bfg, Wig, big, Wug, bug, WT);
    proj_gemm<<<3072, 256, 0, stream>>>(X, WcatT, proj);
    gru_rec<<<64, 512, 0, stream>>>(proj, WT, out);
}